// Round 18
// baseline (1170.674 us; speedup 1.0000x reference)
//
#include <hip/hip_runtime.h>
#include <hip/hip_bf16.h>
#include <math.h>

// MLLA block, round 18 = r13 + gemm_sk __launch_bounds__(256,5) (5 blocks/CU;
// VGPR=64 and LDS=32KB both permit it; prior cap of 4 was the binding limit).
// B=16, L=2304 (48x48), D=384, 12 heads x 32, MLP=1536.

#define L_TOK 2304
#define DIM   384
#define NHEADS 12
#define BATCH 16
#define HIMG  48
#define WIMG  48
#define UNITB ((size_t)L_TOK * DIM)    // 884,736 floats per batch

typedef unsigned short u16;
typedef __attribute__((ext_vector_type(8))) short bf16x8;
typedef __attribute__((ext_vector_type(8))) unsigned short u16x8;
typedef __attribute__((ext_vector_type(4))) float f32x4;

enum { M_BIAS = 0, M_SILU = 1, M_ELU1 = 2, M_GELU = 3, M_RES = 4 };

__device__ __forceinline__ float frcp(float x) { return __builtin_amdgcn_rcpf(x); }
__device__ __forceinline__ float siluf(float x) { return x * frcp(1.0f + __expf(-x)); }
__device__ __forceinline__ float geluf(float x) {   // tanh-form + v_rcp sigmoid
    float t = x * fmaf(x * x, 0.0713548162726f, 1.59576912161f);
    return x * frcp(1.0f + __expf(-t));
}
__device__ __forceinline__ u16 f2bf(float f) {   // HW cvt (RNE on gfx950)
    union { __hip_bfloat16 h; u16 u; } c;
    c.h = __float2bfloat16(f);
    return c.u;
}
__device__ __forceinline__ float bf2f(u16 u) { return __uint_as_float(((unsigned)u) << 16); }
__device__ __forceinline__ float4 bf2f4(ushort4 v) {
    return (float4){bf2f(v.x), bf2f(v.y), bf2f(v.z), bf2f(v.w)};
}
__device__ __forceinline__ void vmwait(int n) {   // n is compile-time post-unroll
    if (n == 0)       asm volatile("s_waitcnt vmcnt(0)" ::: "memory");
    else if (n == 4)  asm volatile("s_waitcnt vmcnt(4)" ::: "memory");
    else if (n == 8)  asm volatile("s_waitcnt vmcnt(8)" ::: "memory");
    else if (n == 12) asm volatile("s_waitcnt vmcnt(12)" ::: "memory");
    else              asm volatile("s_waitcnt vmcnt(0)" ::: "memory");
}

__global__ void sentinel_k(float* out, float v) { out[0] = v; }

// ---------------- weight f32 -> bf16 (n multiple of 1024) ----------------
__global__ __launch_bounds__(256) void cvtw_k(const float* __restrict__ src, u16* __restrict__ dst) {
    int i = blockIdx.x * 256 + threadIdx.x;
    float4 v = ((const float4*)src)[i];
    ushort4 o;
    o.x = f2bf(v.x); o.y = f2bf(v.y); o.z = f2bf(v.z); o.w = f2bf(v.w);
    ((ushort4*)dst)[i] = o;
}

// ---------------- RoPE tables: cos/sin[(h*48+w)*192 + p] ----------------
__global__ __launch_bounds__(256) void rope_tab_k(float* __restrict__ cosT, float* __restrict__ sinT) {
    int i = blockIdx.x * 256 + threadIdx.x;
    if (i >= L_TOK * 192) return;
    int n = i / 192, p = i % 192;
    int h = n / WIMG, w = n % WIMG;
    int j = (p < 96) ? p : p - 96;
    float pos = (p < 96) ? (float)h : (float)w;
    float theta = expf(-(float)j * (9.210340371976184f / 96.0f));  // 10000^(-j/96)
    float ang = pos * theta;
    cosT[i] = cosf(ang);
    sinT[i] = sinf(ang);
}

#define FMA4(s, a, ww) { s.x = fmaf(a.x, ww.x, s.x); s.y = fmaf(a.y, ww.y, s.y); \
                         s.z = fmaf(a.z, ww.z, s.z); s.w = fmaf(a.w, ww.w, s.w); }

// remap a (bx, by) dwconv-style grid so XCD lin&7 owns contiguous strips
__device__ __forceinline__ void dw_remap(int& vbx, int& vby) {
    const int nstr = gridDim.y;                  // nb*4 strips
    vbx = blockIdx.x; vby = blockIdx.y;
    if ((nstr & 7) == 0) {
        const int lin = blockIdx.x + blockIdx.y * gridDim.x;
        const int x = lin & 7, k = lin >> 3;
        vby = x * (nstr >> 3) + k / gridDim.x;
        vbx = k - (k / gridDim.x) * gridDim.x;
    }
}

// ---------------- depthwise 3x3 conv, f32 src, residual: out = src + conv(src) ----------------
__global__ __launch_bounds__(256) void dwconvf_k(const float* __restrict__ src,
                                                 const float* __restrict__ wgt,
                                                 const float* __restrict__ bias,
                                                 float* __restrict__ outf) {
    int vbx, vby;
    dw_remap(vbx, vby);
    const int col = vbx * 256 + threadIdx.x;   // w*96 + cg
    const int strip = vby & 3;
    const int b = vby >> 2;
    const int cg = col % 96, w = col / 96;
    const int rs = WIMG * DIM;
    const size_t ibase = (size_t)b * UNITB + (size_t)w * DIM + cg * 4;
    const float* srcb = src + ibase;
    const float4 z4 = {0.f, 0.f, 0.f, 0.f};
    float4 w9[9];
#pragma unroll
    for (int t = 0; t < 9; ++t) {
        const int c = cg * 4;
        w9[t] = (float4){wgt[(c + 0) * 9 + t], wgt[(c + 1) * 9 + t],
                         wgt[(c + 2) * 9 + t], wgt[(c + 3) * 9 + t]};
    }
    const float4 bv = ((const float4*)bias)[cg];
    float4 A0, A1, A2, B0, B1, B2, C0, C1, C2;
    auto ldrow = [&](int hh, float4& L0, float4& L1, float4& L2) {
        if ((unsigned)hh >= (unsigned)HIMG) { L0 = z4; L1 = z4; L2 = z4; return; }
        const float* p = srcb + (size_t)hh * rs;
        L0 = (w > 0)        ? *(const float4*)(p - DIM) : z4;
        L1 = *(const float4*)p;
        L2 = (w < WIMG - 1) ? *(const float4*)(p + DIM) : z4;
    };
    const int h0 = strip * 12;
    ldrow(h0 - 1, A0, A1, A2);
    ldrow(h0,     B0, B1, B2);
    for (int h = h0; h < h0 + 12; ++h) {
        ldrow(h + 1, C0, C1, C2);
        float4 s = bv;
        FMA4(s, A0, w9[0]); FMA4(s, A1, w9[1]); FMA4(s, A2, w9[2]);
        FMA4(s, B0, w9[3]); FMA4(s, B1, w9[4]); FMA4(s, B2, w9[5]);
        FMA4(s, C0, w9[6]); FMA4(s, C1, w9[7]); FMA4(s, C2, w9[8]);
        const size_t idx = ibase + (size_t)h * rs;
        s.x += B1.x; s.y += B1.y; s.z += B1.z; s.w += B1.w;
        *(float4*)(outf + idx) = s;
        A0 = B0; A1 = B1; A2 = B2;
        B0 = C0; B1 = C1; B2 = C2;
    }
}

// ---------------- depthwise 3x3 conv, bf16 src ----------------
// mode 1 (SILU): out = bf16(silu(conv(src)))
// mode 3 (LEPE): out = bf16((att + conv(src)) * act)
__global__ __launch_bounds__(256) void dwconvb_k(const u16* __restrict__ src,
                                                 const float* __restrict__ wgt,
                                                 const float* __restrict__ bias,
                                                 const u16* __restrict__ att,
                                                 const u16* __restrict__ act,
                                                 u16* __restrict__ outb, int mode) {
    int vbx, vby;
    dw_remap(vbx, vby);
    const int col = vbx * 256 + threadIdx.x;
    const int strip = vby & 3;
    const int b = vby >> 2;
    const int cg = col % 96, w = col / 96;
    const int rs = WIMG * DIM;
    const size_t ibase = (size_t)b * UNITB + (size_t)w * DIM + cg * 4;
    const u16* srcb = src + ibase;
    const float4 z4 = {0.f, 0.f, 0.f, 0.f};
    float4 w9[9];
#pragma unroll
    for (int t = 0; t < 9; ++t) {
        const int c = cg * 4;
        w9[t] = (float4){wgt[(c + 0) * 9 + t], wgt[(c + 1) * 9 + t],
                         wgt[(c + 2) * 9 + t], wgt[(c + 3) * 9 + t]};
    }
    const float4 bv = ((const float4*)bias)[cg];
    float4 A0, A1, A2, B0, B1, B2, C0, C1, C2;
    auto ldrow = [&](int hh, float4& L0, float4& L1, float4& L2) {
        if ((unsigned)hh >= (unsigned)HIMG) { L0 = z4; L1 = z4; L2 = z4; return; }
        const u16* p = srcb + (size_t)hh * rs;
        L0 = (w > 0)        ? bf2f4(*(const ushort4*)(p - DIM)) : z4;
        L1 = bf2f4(*(const ushort4*)p);
        L2 = (w < WIMG - 1) ? bf2f4(*(const ushort4*)(p + DIM)) : z4;
    };
    const int h0 = strip * 12;
    ldrow(h0 - 1, A0, A1, A2);
    ldrow(h0,     B0, B1, B2);
    for (int h = h0; h < h0 + 12; ++h) {
        ldrow(h + 1, C0, C1, C2);
        float4 s = bv;
        FMA4(s, A0, w9[0]); FMA4(s, A1, w9[1]); FMA4(s, A2, w9[2]);
        FMA4(s, B0, w9[3]); FMA4(s, B1, w9[4]); FMA4(s, B2, w9[5]);
        FMA4(s, C0, w9[6]); FMA4(s, C1, w9[7]); FMA4(s, C2, w9[8]);
        const size_t idx = ibase + (size_t)h * rs;
        ushort4 ob;
        if (mode == 1) {
            ob = (ushort4){f2bf(siluf(s.x)), f2bf(siluf(s.y)), f2bf(siluf(s.z)), f2bf(siluf(s.w))};
        } else {
            float4 a4 = bf2f4(*(const ushort4*)(att + idx));
            float4 m4 = bf2f4(*(const ushort4*)(act + idx));
            ob = (ushort4){f2bf((a4.x + s.x) * m4.x), f2bf((a4.y + s.y) * m4.y),
                           f2bf((a4.z + s.z) * m4.z), f2bf((a4.w + s.w) * m4.w)};
        }
        *(ushort4*)(outb + idx) = ob;
        A0 = B0; A1 = B1; A2 = B2;
        B0 = C0; B1 = C1; B2 = C2;
    }
}

// ---------------- LayerNorm over last dim (384) -> bf16, one wave per row ----------------
__global__ __launch_bounds__(256) void ln_k(const float* __restrict__ in,
                                            const float* __restrict__ w,
                                            const float* __restrict__ b,
                                            u16* __restrict__ out) {
    const int dd = blockIdx.x;
    const int vb = (dd & 7) * (gridDim.x >> 3) + (dd >> 3);
    const int row = vb * 4 + (threadIdx.x >> 6);
    const int lane = threadIdx.x & 63;
    const float* x = in + (size_t)row * DIM;
    float v[6];
    float s = 0.f;
#pragma unroll
    for (int i = 0; i < 6; ++i) { v[i] = x[lane + i * 64]; s += v[i]; }
#pragma unroll
    for (int o = 32; o > 0; o >>= 1) s += __shfl_xor(s, o, 64);
    const float mean = s * (1.0f / DIM);
    float q = 0.f;
#pragma unroll
    for (int i = 0; i < 6; ++i) { float d = v[i] - mean; q = fmaf(d, d, q); }
#pragma unroll
    for (int o = 32; o > 0; o >>= 1) q += __shfl_xor(q, o, 64);
    const float rs = 1.0f / sqrtf(q * (1.0f / DIM) + 1e-5f);
    u16* o2 = out + (size_t)row * DIM;
#pragma unroll
    for (int i = 0; i < 6; ++i) {
        int d = lane + i * 64;
        o2[d] = f2bf(fmaf((v[i] - mean) * rs, w[d], b[d]));
    }
}

// ---------------- skinny bf16 MFMA GEMM (r13 form, 5 blocks/CU) ----------------
#define CHK 64
template<int K>
__global__ __launch_bounds__(256, 5) void gemm_sk(const u16* __restrict__ A, int lda,
                                                  const u16* __restrict__ Wt, int ldw,
                                                  const float* __restrict__ bias,
                                                  const float* __restrict__ bias2,
                                                  const float* __restrict__ res,
                                                  float* __restrict__ Cf, u16* __restrict__ Cb,
                                                  u16* __restrict__ Cb2,
                                                  int ldc, int mode, int mode2) {
    constexpr int NT = K / 32;           // K-steps
    constexpr int NCH = K / CHK;         // chunks (= NT/2)
    __shared__ u16 smem[16384];          // exactly 32 KB
    u16* const Bbuf[2] = {smem, smem + 8192};
    const int tid = threadIdx.x;
    const int l = tid & 63;
    const int w = tid >> 6;
    const int fr = l & 15, kb = l >> 4;
    // --- bijective XCD swizzle ---
    const int T = gridDim.x * gridDim.y;
    const int d = blockIdx.y * gridDim.x + blockIdx.x;
    int flat = d;
    if ((T & 7) == 0) { const int q8 = T >> 3; flat = (d & 7) * q8 + (d >> 3); }
    const int n0 = (flat % gridDim.x) * 128;
    const int m0 = (flat / gridDim.x) * 128;
    const int sw = (fr & 7) << 4;

    f32x4 acc[2][8];
#pragma unroll
    for (int i = 0; i < 2; ++i)
#pragma unroll
        for (int j = 0; j < 8; ++j) acc[i][j] = (f32x4){0.f, 0.f, 0.f, 0.f};

    const u16* Ar0 = A + (size_t)(m0 + w * 32 + fr) * lda + kb * 8;
    const u16* Ar1 = Ar0 + (size_t)16 * lda;

    auto STAGE = [&](u16* buf, int cc) {
        const int ck0 = cc * CHK;
#pragma unroll
        for (int q = 0; q < 4; ++q) {
            const int c16 = q * 256 + tid;           // 16B-chunk 0..1023
            const int col = c16 >> 3;                // 8 x16B per col
            const int kb16 = c16 & 7;
            const int koff = ((kb16 * 16) ^ ((col & 7) << 4)) >> 1;   // elements
            const u16* g = Wt + (size_t)(n0 + col) * ldw + ck0 + koff;
            __builtin_amdgcn_global_load_lds(
                (const __attribute__((address_space(1))) void*)g,
                (__attribute__((address_space(3))) void*)(buf + (size_t)(q * 256 + w * 64) * 8),
                16, 0, 0);
        }
    };

    bf16x8 pA[4][2];
    STAGE(Bbuf[0], 0);
    __builtin_amdgcn_sched_barrier(0);
#pragma unroll
    for (int i = 0; i < 4; ++i) {
        pA[i][0] = *(const bf16x8*)(Ar0 + i * 32);
        pA[i][1] = *(const bf16x8*)(Ar1 + i * 32);
    }
    __builtin_amdgcn_sched_barrier(0);
    STAGE(Bbuf[1], 1);
    __builtin_amdgcn_sched_barrier(0);
    vmwait(12);                          // younger: 8 A-loads + 4 stage(c1)
    __builtin_amdgcn_s_barrier();

#pragma unroll
    for (int c = 0; c < NCH; ++c) {
        const u16* bp = Bbuf[c & 1];
#pragma unroll
        for (int ks = 0; ks < 2; ++ks) {
            const int t = 2 * c + ks;
            bf16x8 a0 = pA[t & 3][0], a1 = pA[t & 3][1];
            if (t + 4 < NT) {
                pA[t & 3][0] = *(const bf16x8*)(Ar0 + (t + 4) * 32);
                pA[t & 3][1] = *(const bf16x8*)(Ar1 + (t + 4) * 32);
            }
            const int kpart = (ks * 64 + kb * 16) ^ sw;
            const char* bsb = (const char*)bp + fr * 128 + kpart;
#pragma unroll
            for (int ni = 0; ni < 8; ++ni) {
                bf16x8 bfrag = *(const bf16x8*)(bsb + ni * (16 * 128));
                acc[0][ni] = __builtin_amdgcn_mfma_f32_16x16x32_bf16(a0, bfrag, acc[0][ni], 0, 0, 0);
                acc[1][ni] = __builtin_amdgcn_mfma_f32_16x16x32_bf16(a1, bfrag, acc[1][ni], 0, 0, 0);
            }
        }
        __builtin_amdgcn_sched_barrier(0);
        __builtin_amdgcn_s_barrier();
        __builtin_amdgcn_sched_barrier(0);
        if (c + 2 < NCH) STAGE(Bbuf[c & 1], c + 2);
        __builtin_amdgcn_sched_barrier(0);
        if (c + 1 < NCH)
            vmwait((c < NCH - 2) ? 8 : 0);
    }

    // ---- epilogue ----
    const int orow = (l >> 4) * 4, ocol = l & 15;
    if (Cb != nullptr) {
        const bool is2 = (Cb2 != nullptr) && (n0 >= DIM);
        u16* dst = is2 ? Cb2 : Cb;
        const int ldcs = is2 ? DIM : ldc;
        const int nc0 = is2 ? (n0 - DIM) : n0;
        const float* bp2 = is2 ? bias2 : bias;
        const int md = is2 ? mode2 : mode;
#pragma unroll
        for (int mi = 0; mi < 2; ++mi)
#pragma unroll
            for (int ni = 0; ni < 8; ++ni) {
                const int colL = ni * 16 + ocol;
                const float bv = bp2[nc0 + colL];
#pragma unroll
                for (int r = 0; r < 4; ++r) {
                    const int rowL = w * 32 + mi * 16 + orow + r;
                    float v = acc[mi][ni][r] + bv;
                    if (md == M_SILU)      v = siluf(v);
                    else if (md == M_ELU1) v = (v > 0.f) ? (v + 1.f) : __expf(v);
                    else if (md == M_GELU) v = geluf(v);
                    smem[rowL * 128 + (colL ^ ((rowL & 7) << 3))] = f2bf(v);
                }
            }
        __builtin_amdgcn_s_barrier();
        const int rr = tid >> 4, cc = tid & 15;
#pragma unroll
        for (int it = 0; it < 8; ++it) {
            const int row = it * 16 + rr;
            u16x8 v = *(const u16x8*)&smem[row * 128 + ((cc * 8) ^ ((row & 7) << 3))];
            *(u16x8*)(dst + (size_t)(m0 + row) * ldcs + nc0 + cc * 8) = v;
        }
    } else {
        float* smf = (float*)smem;       // [128][64] f32 = 32KB per pass, 2 passes
#pragma unroll
        for (int p = 0; p < 2; ++p) {
            if (p) __builtin_amdgcn_s_barrier();
#pragma unroll
            for (int mi = 0; mi < 2; ++mi)
#pragma unroll
                for (int ni = 0; ni < 4; ++ni) {
                    const int colL = ni * 16 + ocol;
                    const float bv = bias[n0 + p * 64 + colL];
#pragma unroll
                    for (int r = 0; r < 4; ++r) {
                        const int rowL = w * 32 + mi * 16 + orow + r;
                        float v = acc[mi][p * 4 + ni][r] + bv;
                        if (mode == M_SILU)      v = siluf(v);
                        else if (mode == M_ELU1) v = (v > 0.f) ? (v + 1.f) : __expf(v);
                        else if (mode == M_GELU) v = geluf(v);
                        smf[rowL * 64 + (colL ^ ((rowL & 3) << 4))] = v;
                    }
                }
            __builtin_amdgcn_s_barrier();
            const int rr = tid >> 4, cc = tid & 15;
#pragma unroll
            for (int it = 0; it < 8; ++it) {
                const int row = it * 16 + rr;
                float4 v = *(const float4*)&smf[row * 64 + ((cc * 4) ^ ((row & 3) << 4))];
                const size_t oi = (size_t)(m0 + row) * ldc + n0 + p * 64 + cc * 4;
                if (res) {
                    float4 rv = *(const float4*)(res + oi);
                    v.x += rv.x; v.y += rv.y; v.z += rv.z; v.w += rv.w;
                }
                *(float4*)(Cf + oi) = v;
            }
        }
    }
}

// ---------------- kmean: column mean of k (bf16, M x 384), two-stage ----------------
__global__ __launch_bounds__(384) void kmean_part_k(const u16* __restrict__ kbuf, float* __restrict__ part, int nb) {
    const int b = blockIdx.x, chunk = blockIdx.y;   // nb x 9
    const int c = threadIdx.x;
    const u16* p = kbuf + ((size_t)(b * L_TOK + chunk * 256)) * DIM + c;
    float s = 0.f;
    for (int n = 0; n < 256; ++n) s += bf2f(p[(size_t)n * DIM]);
    part[(size_t)(chunk * nb + b) * DIM + c] = s;
}

__global__ __launch_bounds__(384) void kmean_fin_k(const float* __restrict__ part, float* __restrict__ km, int nb) {
    const int b = blockIdx.x, c = threadIdx.x;
    float s = 0.f;
#pragma unroll
    for (int ch = 0; ch < 9; ++ch) s += part[(size_t)(ch * nb + b) * DIM + c];
    km[b * DIM + c] = s * (1.0f / L_TOK);
}

// ---------------- z: z[row] = 1/(q[row,:]·km[b,:] + 1e-6), one wave per row ----------------
__global__ __launch_bounds__(256) void z_k(const u16* __restrict__ q, const float* __restrict__ km,
                                           float* __restrict__ z) {
    const int dd = blockIdx.x;
    const int vb = (dd & 7) * (gridDim.x >> 3) + (dd >> 3);
    const int row = vb * 4 + (threadIdx.x >> 6);
    const int lane = threadIdx.x & 63;
    const int b = row / L_TOK;
    const u16* qr = q + (size_t)row * DIM;
    const float* kb = km + b * DIM;
    float s = 0.f;
#pragma unroll
    for (int i = 0; i < 6; ++i) { int c = lane + i * 64; s += bf2f(qr[c]) * kb[c]; }
#pragma unroll
    for (int o = 32; o > 0; o >>= 1) s += __shfl_xor(s, o, 64);
    if (lane == 0) z[row] = 1.0f / (s + 1e-6f);
}

// ---------------- kv partials: 4 n-chunks of 576 tokens each ----------------
__global__ __launch_bounds__(256) void kv_part_k(const u16* __restrict__ kbuf, const u16* __restrict__ xi,
                                                 const float* __restrict__ cosT, const float* __restrict__ sinT,
                                                 float* __restrict__ part) {
    const int bh = blockIdx.x >> 2, chunk = blockIdx.x & 3;
    const int b = bh / NHEADS, h = bh % NHEADS;
    __shared__ float ks[64][33];
    __shared__ float vs[64][33];
    const int tid = threadIdx.x;
    const int e0 = (tid & 15) * 2;
    const int d0 = (tid >> 4) * 2;
    float acc00 = 0.f, acc01 = 0.f, acc10 = 0.f, acc11 = 0.f;
    const int nbeg = chunk * 576, nend = nbeg + 576;
    for (int n0 = nbeg; n0 < nend; n0 += 64) {
#pragma unroll
        for (int j = 0; j < 4; ++j) {           // 1024 rope pairs
            int pi = tid + j * 256;
            int tn = pi >> 4;
            int pd = pi & 15;
            int n = n0 + tn;
            unsigned kk = *(const unsigned*)(kbuf + ((size_t)(b * L_TOK + n)) * DIM + h * 32 + pd * 2);
            float ka = bf2f((u16)(kk & 0xffffu)), kb2 = bf2f((u16)(kk >> 16));
            float cs = cosT[n * 192 + h * 16 + pd];
            float sn = sinT[n * 192 + h * 16 + pd];
            ks[tn][pd * 2]     = cs * ka - sn * kb2;
            ks[tn][pd * 2 + 1] = sn * ka + cs * kb2;
        }
#pragma unroll
        for (int j = 0; j < 4; ++j) {           // 2048 v elems as u16 pairs
            int pi = tid + j * 256;
            int tn = pi >> 4;
            int dd = (pi & 15) * 2;
            unsigned vv = *(const unsigned*)(xi + ((size_t)(b * L_TOK + n0 + tn)) * DIM + h * 32 + dd);
            vs[tn][dd]     = bf2f((u16)(vv & 0xffffu));
            vs[tn][dd + 1] = bf2f((u16)(vv >> 16));
        }
        __syncthreads();
#pragma unroll 8
        for (int n = 0; n < 64; ++n) {
            float k0v = ks[n][d0], k1v = ks[n][d0 + 1];
            float v0 = vs[n][e0], v1 = vs[n][e0 + 1];
            acc00 = fmaf(k0v, v0, acc00);
            acc01 = fmaf(k0v, v1, acc01);
            acc10 = fmaf(k1v, v0, acc10);
            acc11 = fmaf(k1v, v1, acc11);
        }
        __syncthreads();
    }
    float* o = part + ((size_t)blockIdx.x * 32 + d0) * 32 + e0;
    o[0] = acc00; o[1] = acc01;
    o[32] = acc10; o[33] = acc11;
}

// kv finalize -> bf16 TRANSPOSED: kvt[bh][e][d] = (1/L) * sum_chunks part[bh][d][e]
__global__ __launch_bounds__(256) void kv_fin_k(const float* __restrict__ part, u16* __restrict__ kvt) {
    const int bh = blockIdx.x;
    const int tid = threadIdx.x;
#pragma unroll
    for (int i = tid; i < 1024; i += 256) {
        const int e = i >> 5, dd = i & 31;
        float s = 0.f;
#pragma unroll
        for (int c = 0; c < 4; ++c) s += part[((size_t)(bh * 4 + c)) * 1024 + dd * 32 + e];
        kvt[(size_t)bh * 1024 + i] = f2bf(s * (1.0f / L_TOK));
    }
}

// ---------------- attention as MFMA ----------------
__global__ __launch_bounds__(256) void attm_k(const u16* __restrict__ q, const u16* __restrict__ kvt,
                                              const float* __restrict__ z,
                                              const float* __restrict__ cosT, const float* __restrict__ sinT,
                                              u16* __restrict__ out) {
    __shared__ u16 ost[128 * 32];        // 8 KB coalesce stage
    const int tid = threadIdx.x, l = tid & 63, w = tid >> 6;
    const int b = blockIdx.y / NHEADS, h = blockIdx.y % NHEADS;
    const int m0 = blockIdx.x * 128;
    const int fr = l & 15, kb = l >> 4;

    f32x4 acc[2][2];
#pragma unroll
    for (int i = 0; i < 2; ++i)
#pragma unroll
        for (int j = 0; j < 2; ++j) acc[i][j] = (f32x4){0.f, 0.f, 0.f, 0.f};

    const int p0 = h * 16 + kb * 4;      // rope pair base for this lane's 8 channels
    bf16x8 afr[2];
#pragma unroll
    for (int mi = 0; mi < 2; ++mi) {
        const int n = m0 + w * 32 + mi * 16 + fr;            // token index
        bf16x8 raw = *(const bf16x8*)(q + ((size_t)(b * L_TOK + n)) * DIM + h * 32 + kb * 8);
        float4 cs = *(const float4*)(cosT + (size_t)n * 192 + p0);
        float4 sn = *(const float4*)(sinT + (size_t)n * 192 + p0);
        union { u16 u[8]; bf16x8 v; } pk;
        float a0, a1;
        a0 = bf2f((u16)raw[0]); a1 = bf2f((u16)raw[1]);
        pk.u[0] = f2bf(cs.x * a0 - sn.x * a1); pk.u[1] = f2bf(sn.x * a0 + cs.x * a1);
        a0 = bf2f((u16)raw[2]); a1 = bf2f((u16)raw[3]);
        pk.u[2] = f2bf(cs.y * a0 - sn.y * a1); pk.u[3] = f2bf(sn.y * a0 + cs.y * a1);
        a0 = bf2f((u16)raw[4]); a1 = bf2f((u16)raw[5]);
        pk.u[4] = f2bf(cs.z * a0 - sn.z * a1); pk.u[5] = f2bf(sn.z * a0 + cs.z * a1);
        a0 = bf2f((u16)raw[6]); a1 = bf2f((u16)raw[7]);
        pk.u[6] = f2bf(cs.w * a0 - sn.w * a1); pk.u[7] = f2bf(sn.w * a0 + cs.w * a1);
        afr[mi] = pk.v;
    }
    bf16x8 bfr[2];
    const u16* kvh = kvt + (size_t)(b * NHEADS + h) * 1024;
#pragma unroll
    for (int ni = 0; ni < 2; ++ni)
        bfr[ni] = *(const bf16x8*)(kvh + (ni * 16 + fr) * 32 + kb * 8);
#pragma unroll
    for (int mi = 0; mi < 2; ++mi)
#pragma unroll
        for (int ni = 0; ni < 2; ++ni)
            acc[mi][ni] = __builtin_amdgcn_mfma_f32_16x16x32_bf16(afr[mi], bfr[ni], acc[mi][ni], 0, 0, 0);

    // epilogue: scale by z, stage to LDS, coalesced store
    const int orow = (l >> 4) * 4, ocol = l & 15;
#pragma unroll
    for (int mi = 0; mi < 2; ++mi) {
        float zz[4];
#pragma unroll
        for (int r = 0; r < 4; ++r)
            zz[r] = z[b * L_TOK + m0 + w * 32 + mi * 16 + orow + r];
#pragma unroll
        for (int ni = 0; ni < 2; ++ni) {
#pragma unroll
            for (int r = 0; r < 4; ++r) {
                const int rowL = w * 32 + mi * 16 + orow + r;
                ost[rowL * 32 + ni * 16 + ocol] = f2bf(acc[mi][ni][r] * zz[r]);
            }
        }
    }
    __syncthreads();
#pragma unroll
    for (int it = 0; it < 2; ++it) {
        const int ch = it * 256 + tid;               // 0..511
        const int row = ch >> 2, c8 = (ch & 3) * 8;
        u16x8 v = *(const u16x8*)&ost[row * 32 + c8];
        *(u16x8*)(out + ((size_t)(b * L_TOK + m0 + row)) * DIM + h * 32 + c8) = v;
    }
}

extern "C" void kernel_launch(void* const* d_in, const int* in_sizes, int n_in,
                              void* d_out, int out_size, void* d_ws, size_t ws_size,
                              hipStream_t stream) {
    const float* x       = (const float*)d_in[0];
    const float* cpe1_w  = (const float*)d_in[3];
    const float* cpe1_b  = (const float*)d_in[4];
    const float* norm1_w = (const float*)d_in[5];
    const float* norm1_b = (const float*)d_in[6];
    const float* in_w    = (const float*)d_in[7];
    const float* in_b    = (const float*)d_in[8];
    const float* act_w   = (const float*)d_in[9];
    const float* act_b   = (const float*)d_in[10];
    const float* dwc_w   = (const float*)d_in[11];
    const float* dwc_b   = (const float*)d_in[12];
    const float* qk_w    = (const float*)d_in[13];
    const float* qk_b    = (const float*)d_in[14];
    const float* lepe_w  = (const float*)d_in[15];
    const float* lepe_b  = (const float*)d_in[16];
    const float* outp_w  = (const float*)d_in[17];
    const float* outp_b  = (const float*)d_in[18];
    const float* cpe2_w  = (const float*)d_in[19];
    const float* cpe2_b  = (const float*)d_in[20];
    const float* norm2_w = (const float*)d_in[21];
    const float* norm2_b = (const float*)d_in[22];
    const float* fc1_w   = (const float*)d_in[23];
    const float* fc1_b   = (const float*)d_in[24];
    const float* fc2_w   = (const float*)d_in[25];
    const float* fc2_b   = (const float*)d_in[26];
    float* out = (float*)d_out;

    float* ws = (float*)d_ws;
    const size_t TAB = (size_t)L_TOK * 192;
    const size_t NW_IN = 147456, NW_QK = 294912, NW_FC = 589824;
    const size_t WBF_U16 = NW_IN * 3 + NW_QK + NW_FC * 2;
    const size_t KVP = 4 * (size_t)BATCH * NHEADS * 1024;          // kv partials
    const size_t ZB  = (size_t)BATCH * L_TOK;                      // z buffer
    const size_t SMALL = 2 * TAB + (size_t)BATCH * DIM + 9 * (size_t)BATCH * DIM
                       + (size_t)BATCH * NHEADS * 1024 + KVP + ZB + WBF_U16 / 2;
    float* cosT = ws;
    float* sinT = cosT + TAB;
    float* km   = sinT + TAB;
    float* part = km + (size_t)BATCH * DIM;
    float* kvb  = part + 9 * (size_t)BATCH * DIM;                  // kvt lives here (u16, half used)
    float* kvp  = kvb + (size_t)BATCH * NHEADS * 1024;
    float* zb   = kvp + KVP;
    u16*   kvt  = (u16*)kvb;
    u16*   wb_in  = (u16*)(zb + ZB);                               // [in_w; act_w] = 768x384
    u16*   wb_act = wb_in + NW_IN;
    u16*   wb_qk  = wb_act + NW_IN;                                // 768x384
    u16*   wb_out = wb_qk + NW_QK;
    u16*   wb_fc1 = wb_out + NW_IN;
    u16*   wb_fc2 = wb_fc1 + NW_FC;
    float* gbuf = ws + SMALL;

    const size_t avail = (ws_size / 4 > SMALL) ? (ws_size / 4 - SMALL) : 0;
    int nb = 0;
    for (int cand = BATCH; cand >= 1; cand >>= 1)
        if (9 * (size_t)cand * UNITB / 2 <= avail) { nb = cand; break; }
    if (nb == 0) {
        sentinel_k<<<1, 1, 0, stream>>>(out, (float)(ws_size >> 20));
        return;
    }

    cvtw_k<<<(int)(NW_IN / 1024), 256, 0, stream>>>(in_w, wb_in);
    cvtw_k<<<(int)(NW_IN / 1024), 256, 0, stream>>>(act_w, wb_act);
    cvtw_k<<<(int)(NW_QK / 1024), 256, 0, stream>>>(qk_w, wb_qk);
    cvtw_k<<<(int)(NW_IN / 1024), 256, 0, stream>>>(outp_w, wb_out);
    cvtw_k<<<(int)(NW_FC / 1024), 256, 0, stream>>>(fc1_w, wb_fc1);
    cvtw_k<<<(int)(NW_FC / 1024), 256, 0, stream>>>(fc2_w, wb_fc2);
    rope_tab_k<<<(int)((TAB + 255) / 256), 256, 0, stream>>>(cosT, sinT);

    for (int b0 = 0; b0 < BATCH; b0 += nb) {
        const size_t goff = (size_t)b0 * UNITB;
        const size_t GU   = (size_t)nb * UNITB;
        float* W0 = gbuf;             // x1 / x3 (f32 residual chain)
        float* W1 = gbuf + GU;        // xn(bf16) / q(bf16) / ao(bf16) / xn2(bf16)
        float* W2 = gbuf + 2 * GU;    // xi0+act_res(bf16) / x2(f32) / h(bf16, W2+W3)
        u16*   Wb = (u16*)(gbuf + 4 * GU);   // xi (bf16)
        float* O  = out + goff;       // k(bf16) / att(bf16) / final out (f32)
        const float* Xg = x + goff;
        u16* xi0p = (u16*)W2;         // xi0 bf16 (GU u16)
        u16* actp = (u16*)W2 + GU;    // act_res bf16 (GU u16)

        const dim3 DWG(18, nb * 4);
        const dim3 G384(3, nb * 18), G768(6, nb * 18), G1536(12, nb * 18);

        // x1 = x + dwconv(x, cpe1) -> W0 f32
        dwconvf_k<<<DWG, 256, 0, stream>>>(Xg, cpe1_w, cpe1_b, W0);
        // xn = LN(x1) -> W1 bf16
        ln_k<<<nb * 576, 256, 0, stream>>>(W0, norm1_w, norm1_b, (u16*)W1);
        // fused: xi0 = xn@in^T+b (cols<384) ; act_res = silu(xn@act^T+b) (cols>=384)
        gemm_sk<384><<<G768, 256, 0, stream>>>((u16*)W1, DIM, wb_in, DIM, in_b, act_b, nullptr,
                                               nullptr, xi0p, actp, DIM, M_BIAS, M_SILU);
        // xi = silu(dwconv(xi0, dwc)) -> Wb bf16
        dwconvb_k<<<DWG, 256, 0, stream>>>(xi0p, dwc_w, dwc_b, nullptr, nullptr, Wb, 1);
        // fused: q = elu(xi@qk[:384]^T+b)+1 -> W1 ; k = elu(xi@qk[384:]^T+b)+1 -> O
        gemm_sk<384><<<G768, 256, 0, stream>>>(Wb, DIM, wb_qk, DIM, qk_b, qk_b + DIM, nullptr,
                                               nullptr, (u16*)W1, (u16*)O, DIM, M_ELU1, M_ELU1);
        // kmean over k (bf16)
        kmean_part_k<<<dim3(nb, 9), 384, 0, stream>>>((u16*)O, part, nb);
        kmean_fin_k<<<nb, 384, 0, stream>>>(part, km, nb);
        // z = 1/(q·km + eps)
        z_k<<<nb * 576, 256, 0, stream>>>((u16*)W1, km, zb);
        // kv from rope(k), v=xi: 4-way n-chunked partials + bf16-transposed reduce
        kv_part_k<<<nb * NHEADS * 4, 256, 0, stream>>>((u16*)O, Wb, cosT, sinT, kvp);
        kv_fin_k<<<nb * NHEADS, 256, 0, stream>>>(kvp, kvt);
        // att = z * (rope(q) @ kv) -> O bf16 (overwrites k), MFMA path
        attm_k<<<dim3(18, nb * NHEADS), 256, 0, stream>>>((u16*)W1, kvt, zb, cosT, sinT, (u16*)O);
        // ao = (att + dwconv(xi, lepe)) * act_res -> W1 bf16
        dwconvb_k<<<DWG, 256, 0, stream>>>(Wb, lepe_w, lepe_b, (const u16*)O, actp,
                                           (u16*)W1, 3);
        // x2 = x1 + ao @ out_proj^T + b -> W2 f32 (act_res dead now)
        gemm_sk<384><<<G384, 256, 0, stream>>>((u16*)W1, DIM, wb_out, DIM, outp_b, nullptr, W0,
                                               W2, nullptr, nullptr, DIM, M_RES, M_RES);
        // x3 = x2 + dwconv(x2, cpe2) -> W0 f32
        dwconvf_k<<<DWG, 256, 0, stream>>>(W2, cpe2_w, cpe2_b, W0);
        // xn2 = LN(x3) -> W1 bf16
        ln_k<<<nb * 576, 256, 0, stream>>>(W0, norm2_w, norm2_b, (u16*)W1);
        // h = gelu(xn2 @ fc1^T + b) -> W2+W3 bf16
        gemm_sk<384><<<G1536, 256, 0, stream>>>((u16*)W1, DIM, wb_fc1, DIM, fc1_b, nullptr, nullptr,
                                                nullptr, (u16*)W2, nullptr, 1536, M_GELU, M_GELU);
        // O = x3 + h @ fc2^T + b2  (final, f32)
        gemm_sk<1536><<<G384, 256, 0, stream>>>((u16*)W2, 1536, wb_fc2, 1536, fc2_b, nullptr, W0,
                                                O, nullptr, nullptr, DIM, M_RES, M_RES);
    }
}

// Round 19
// 508.799 us; speedup vs baseline: 2.3009x; 2.3009x over previous
//
#include <hip/hip_runtime.h>
#include <hip/hip_bf16.h>
#include <math.h>

// MLLA block, round 19 = r13/r17 verbatim (verified best, 510-515 us).
// r18's launch_bounds(256,5) forced VGPR 64->48 => accumulator spill
// (WRITE_SIZE 55->600 MB). Reverted to (256,4). Final configuration.
// B=16, L=2304 (48x48), D=384, 12 heads x 32, MLP=1536.

#define L_TOK 2304
#define DIM   384
#define NHEADS 12
#define BATCH 16
#define HIMG  48
#define WIMG  48
#define UNITB ((size_t)L_TOK * DIM)    // 884,736 floats per batch

typedef unsigned short u16;
typedef __attribute__((ext_vector_type(8))) short bf16x8;
typedef __attribute__((ext_vector_type(8))) unsigned short u16x8;
typedef __attribute__((ext_vector_type(4))) float f32x4;

enum { M_BIAS = 0, M_SILU = 1, M_ELU1 = 2, M_GELU = 3, M_RES = 4 };

__device__ __forceinline__ float frcp(float x) { return __builtin_amdgcn_rcpf(x); }
__device__ __forceinline__ float siluf(float x) { return x * frcp(1.0f + __expf(-x)); }
__device__ __forceinline__ float geluf(float x) {   // tanh-form + v_rcp sigmoid
    float t = x * fmaf(x * x, 0.0713548162726f, 1.59576912161f);
    return x * frcp(1.0f + __expf(-t));
}
__device__ __forceinline__ u16 f2bf(float f) {   // HW cvt (RNE on gfx950)
    union { __hip_bfloat16 h; u16 u; } c;
    c.h = __float2bfloat16(f);
    return c.u;
}
__device__ __forceinline__ float bf2f(u16 u) { return __uint_as_float(((unsigned)u) << 16); }
__device__ __forceinline__ float4 bf2f4(ushort4 v) {
    return (float4){bf2f(v.x), bf2f(v.y), bf2f(v.z), bf2f(v.w)};
}
__device__ __forceinline__ void vmwait(int n) {   // n is compile-time post-unroll
    if (n == 0)       asm volatile("s_waitcnt vmcnt(0)" ::: "memory");
    else if (n == 4)  asm volatile("s_waitcnt vmcnt(4)" ::: "memory");
    else if (n == 8)  asm volatile("s_waitcnt vmcnt(8)" ::: "memory");
    else if (n == 12) asm volatile("s_waitcnt vmcnt(12)" ::: "memory");
    else              asm volatile("s_waitcnt vmcnt(0)" ::: "memory");
}

__global__ void sentinel_k(float* out, float v) { out[0] = v; }

// ---------------- weight f32 -> bf16 (n multiple of 1024) ----------------
__global__ __launch_bounds__(256) void cvtw_k(const float* __restrict__ src, u16* __restrict__ dst) {
    int i = blockIdx.x * 256 + threadIdx.x;
    float4 v = ((const float4*)src)[i];
    ushort4 o;
    o.x = f2bf(v.x); o.y = f2bf(v.y); o.z = f2bf(v.z); o.w = f2bf(v.w);
    ((ushort4*)dst)[i] = o;
}

// ---------------- RoPE tables: cos/sin[(h*48+w)*192 + p] ----------------
__global__ __launch_bounds__(256) void rope_tab_k(float* __restrict__ cosT, float* __restrict__ sinT) {
    int i = blockIdx.x * 256 + threadIdx.x;
    if (i >= L_TOK * 192) return;
    int n = i / 192, p = i % 192;
    int h = n / WIMG, w = n % WIMG;
    int j = (p < 96) ? p : p - 96;
    float pos = (p < 96) ? (float)h : (float)w;
    float theta = expf(-(float)j * (9.210340371976184f / 96.0f));  // 10000^(-j/96)
    float ang = pos * theta;
    cosT[i] = cosf(ang);
    sinT[i] = sinf(ang);
}

#define FMA4(s, a, ww) { s.x = fmaf(a.x, ww.x, s.x); s.y = fmaf(a.y, ww.y, s.y); \
                         s.z = fmaf(a.z, ww.z, s.z); s.w = fmaf(a.w, ww.w, s.w); }

// remap a (bx, by) dwconv-style grid so XCD lin&7 owns contiguous strips
__device__ __forceinline__ void dw_remap(int& vbx, int& vby) {
    const int nstr = gridDim.y;                  // nb*4 strips
    vbx = blockIdx.x; vby = blockIdx.y;
    if ((nstr & 7) == 0) {
        const int lin = blockIdx.x + blockIdx.y * gridDim.x;
        const int x = lin & 7, k = lin >> 3;
        vby = x * (nstr >> 3) + k / gridDim.x;
        vbx = k - (k / gridDim.x) * gridDim.x;
    }
}

// ---------------- depthwise 3x3 conv, f32 src, residual: out = src + conv(src) ----------------
__global__ __launch_bounds__(256) void dwconvf_k(const float* __restrict__ src,
                                                 const float* __restrict__ wgt,
                                                 const float* __restrict__ bias,
                                                 float* __restrict__ outf) {
    int vbx, vby;
    dw_remap(vbx, vby);
    const int col = vbx * 256 + threadIdx.x;   // w*96 + cg
    const int strip = vby & 3;
    const int b = vby >> 2;
    const int cg = col % 96, w = col / 96;
    const int rs = WIMG * DIM;
    const size_t ibase = (size_t)b * UNITB + (size_t)w * DIM + cg * 4;
    const float* srcb = src + ibase;
    const float4 z4 = {0.f, 0.f, 0.f, 0.f};
    float4 w9[9];
#pragma unroll
    for (int t = 0; t < 9; ++t) {
        const int c = cg * 4;
        w9[t] = (float4){wgt[(c + 0) * 9 + t], wgt[(c + 1) * 9 + t],
                         wgt[(c + 2) * 9 + t], wgt[(c + 3) * 9 + t]};
    }
    const float4 bv = ((const float4*)bias)[cg];
    float4 A0, A1, A2, B0, B1, B2, C0, C1, C2;
    auto ldrow = [&](int hh, float4& L0, float4& L1, float4& L2) {
        if ((unsigned)hh >= (unsigned)HIMG) { L0 = z4; L1 = z4; L2 = z4; return; }
        const float* p = srcb + (size_t)hh * rs;
        L0 = (w > 0)        ? *(const float4*)(p - DIM) : z4;
        L1 = *(const float4*)p;
        L2 = (w < WIMG - 1) ? *(const float4*)(p + DIM) : z4;
    };
    const int h0 = strip * 12;
    ldrow(h0 - 1, A0, A1, A2);
    ldrow(h0,     B0, B1, B2);
    for (int h = h0; h < h0 + 12; ++h) {
        ldrow(h + 1, C0, C1, C2);
        float4 s = bv;
        FMA4(s, A0, w9[0]); FMA4(s, A1, w9[1]); FMA4(s, A2, w9[2]);
        FMA4(s, B0, w9[3]); FMA4(s, B1, w9[4]); FMA4(s, B2, w9[5]);
        FMA4(s, C0, w9[6]); FMA4(s, C1, w9[7]); FMA4(s, C2, w9[8]);
        const size_t idx = ibase + (size_t)h * rs;
        s.x += B1.x; s.y += B1.y; s.z += B1.z; s.w += B1.w;
        *(float4*)(outf + idx) = s;
        A0 = B0; A1 = B1; A2 = B2;
        B0 = C0; B1 = C1; B2 = C2;
    }
}

// ---------------- depthwise 3x3 conv, bf16 src ----------------
// mode 1 (SILU): out = bf16(silu(conv(src)))
// mode 3 (LEPE): out = bf16((att + conv(src)) * act)
__global__ __launch_bounds__(256) void dwconvb_k(const u16* __restrict__ src,
                                                 const float* __restrict__ wgt,
                                                 const float* __restrict__ bias,
                                                 const u16* __restrict__ att,
                                                 const u16* __restrict__ act,
                                                 u16* __restrict__ outb, int mode) {
    int vbx, vby;
    dw_remap(vbx, vby);
    const int col = vbx * 256 + threadIdx.x;
    const int strip = vby & 3;
    const int b = vby >> 2;
    const int cg = col % 96, w = col / 96;
    const int rs = WIMG * DIM;
    const size_t ibase = (size_t)b * UNITB + (size_t)w * DIM + cg * 4;
    const u16* srcb = src + ibase;
    const float4 z4 = {0.f, 0.f, 0.f, 0.f};
    float4 w9[9];
#pragma unroll
    for (int t = 0; t < 9; ++t) {
        const int c = cg * 4;
        w9[t] = (float4){wgt[(c + 0) * 9 + t], wgt[(c + 1) * 9 + t],
                         wgt[(c + 2) * 9 + t], wgt[(c + 3) * 9 + t]};
    }
    const float4 bv = ((const float4*)bias)[cg];
    float4 A0, A1, A2, B0, B1, B2, C0, C1, C2;
    auto ldrow = [&](int hh, float4& L0, float4& L1, float4& L2) {
        if ((unsigned)hh >= (unsigned)HIMG) { L0 = z4; L1 = z4; L2 = z4; return; }
        const u16* p = srcb + (size_t)hh * rs;
        L0 = (w > 0)        ? bf2f4(*(const ushort4*)(p - DIM)) : z4;
        L1 = bf2f4(*(const ushort4*)p);
        L2 = (w < WIMG - 1) ? bf2f4(*(const ushort4*)(p + DIM)) : z4;
    };
    const int h0 = strip * 12;
    ldrow(h0 - 1, A0, A1, A2);
    ldrow(h0,     B0, B1, B2);
    for (int h = h0; h < h0 + 12; ++h) {
        ldrow(h + 1, C0, C1, C2);
        float4 s = bv;
        FMA4(s, A0, w9[0]); FMA4(s, A1, w9[1]); FMA4(s, A2, w9[2]);
        FMA4(s, B0, w9[3]); FMA4(s, B1, w9[4]); FMA4(s, B2, w9[5]);
        FMA4(s, C0, w9[6]); FMA4(s, C1, w9[7]); FMA4(s, C2, w9[8]);
        const size_t idx = ibase + (size_t)h * rs;
        ushort4 ob;
        if (mode == 1) {
            ob = (ushort4){f2bf(siluf(s.x)), f2bf(siluf(s.y)), f2bf(siluf(s.z)), f2bf(siluf(s.w))};
        } else {
            float4 a4 = bf2f4(*(const ushort4*)(att + idx));
            float4 m4 = bf2f4(*(const ushort4*)(act + idx));
            ob = (ushort4){f2bf((a4.x + s.x) * m4.x), f2bf((a4.y + s.y) * m4.y),
                           f2bf((a4.z + s.z) * m4.z), f2bf((a4.w + s.w) * m4.w)};
        }
        *(ushort4*)(outb + idx) = ob;
        A0 = B0; A1 = B1; A2 = B2;
        B0 = C0; B1 = C1; B2 = C2;
    }
}

// ---------------- LayerNorm over last dim (384) -> bf16, one wave per row ----------------
__global__ __launch_bounds__(256) void ln_k(const float* __restrict__ in,
                                            const float* __restrict__ w,
                                            const float* __restrict__ b,
                                            u16* __restrict__ out) {
    const int dd = blockIdx.x;
    const int vb = (dd & 7) * (gridDim.x >> 3) + (dd >> 3);
    const int row = vb * 4 + (threadIdx.x >> 6);
    const int lane = threadIdx.x & 63;
    const float* x = in + (size_t)row * DIM;
    float v[6];
    float s = 0.f;
#pragma unroll
    for (int i = 0; i < 6; ++i) { v[i] = x[lane + i * 64]; s += v[i]; }
#pragma unroll
    for (int o = 32; o > 0; o >>= 1) s += __shfl_xor(s, o, 64);
    const float mean = s * (1.0f / DIM);
    float q = 0.f;
#pragma unroll
    for (int i = 0; i < 6; ++i) { float d = v[i] - mean; q = fmaf(d, d, q); }
#pragma unroll
    for (int o = 32; o > 0; o >>= 1) q += __shfl_xor(q, o, 64);
    const float rs = 1.0f / sqrtf(q * (1.0f / DIM) + 1e-5f);
    u16* o2 = out + (size_t)row * DIM;
#pragma unroll
    for (int i = 0; i < 6; ++i) {
        int d = lane + i * 64;
        o2[d] = f2bf(fmaf((v[i] - mean) * rs, w[d], b[d]));
    }
}

// ---------------- skinny bf16 MFMA GEMM (r13 form, 4 blocks/CU) ----------------
#define CHK 64
template<int K>
__global__ __launch_bounds__(256, 4) void gemm_sk(const u16* __restrict__ A, int lda,
                                                  const u16* __restrict__ Wt, int ldw,
                                                  const float* __restrict__ bias,
                                                  const float* __restrict__ bias2,
                                                  const float* __restrict__ res,
                                                  float* __restrict__ Cf, u16* __restrict__ Cb,
                                                  u16* __restrict__ Cb2,
                                                  int ldc, int mode, int mode2) {
    constexpr int NT = K / 32;           // K-steps
    constexpr int NCH = K / CHK;         // chunks (= NT/2)
    __shared__ u16 smem[16384];          // exactly 32 KB
    u16* const Bbuf[2] = {smem, smem + 8192};
    const int tid = threadIdx.x;
    const int l = tid & 63;
    const int w = tid >> 6;
    const int fr = l & 15, kb = l >> 4;
    // --- bijective XCD swizzle ---
    const int T = gridDim.x * gridDim.y;
    const int d = blockIdx.y * gridDim.x + blockIdx.x;
    int flat = d;
    if ((T & 7) == 0) { const int q8 = T >> 3; flat = (d & 7) * q8 + (d >> 3); }
    const int n0 = (flat % gridDim.x) * 128;
    const int m0 = (flat / gridDim.x) * 128;
    const int sw = (fr & 7) << 4;

    f32x4 acc[2][8];
#pragma unroll
    for (int i = 0; i < 2; ++i)
#pragma unroll
        for (int j = 0; j < 8; ++j) acc[i][j] = (f32x4){0.f, 0.f, 0.f, 0.f};

    const u16* Ar0 = A + (size_t)(m0 + w * 32 + fr) * lda + kb * 8;
    const u16* Ar1 = Ar0 + (size_t)16 * lda;

    auto STAGE = [&](u16* buf, int cc) {
        const int ck0 = cc * CHK;
#pragma unroll
        for (int q = 0; q < 4; ++q) {
            const int c16 = q * 256 + tid;           // 16B-chunk 0..1023
            const int col = c16 >> 3;                // 8 x16B per col
            const int kb16 = c16 & 7;
            const int koff = ((kb16 * 16) ^ ((col & 7) << 4)) >> 1;   // elements
            const u16* g = Wt + (size_t)(n0 + col) * ldw + ck0 + koff;
            __builtin_amdgcn_global_load_lds(
                (const __attribute__((address_space(1))) void*)g,
                (__attribute__((address_space(3))) void*)(buf + (size_t)(q * 256 + w * 64) * 8),
                16, 0, 0);
        }
    };

    bf16x8 pA[4][2];
    STAGE(Bbuf[0], 0);
    __builtin_amdgcn_sched_barrier(0);
#pragma unroll
    for (int i = 0; i < 4; ++i) {
        pA[i][0] = *(const bf16x8*)(Ar0 + i * 32);
        pA[i][1] = *(const bf16x8*)(Ar1 + i * 32);
    }
    __builtin_amdgcn_sched_barrier(0);
    STAGE(Bbuf[1], 1);
    __builtin_amdgcn_sched_barrier(0);
    vmwait(12);                          // younger: 8 A-loads + 4 stage(c1)
    __builtin_amdgcn_s_barrier();

#pragma unroll
    for (int c = 0; c < NCH; ++c) {
        const u16* bp = Bbuf[c & 1];
#pragma unroll
        for (int ks = 0; ks < 2; ++ks) {
            const int t = 2 * c + ks;
            bf16x8 a0 = pA[t & 3][0], a1 = pA[t & 3][1];
            if (t + 4 < NT) {
                pA[t & 3][0] = *(const bf16x8*)(Ar0 + (t + 4) * 32);
                pA[t & 3][1] = *(const bf16x8*)(Ar1 + (t + 4) * 32);
            }
            const int kpart = (ks * 64 + kb * 16) ^ sw;
            const char* bsb = (const char*)bp + fr * 128 + kpart;
#pragma unroll
            for (int ni = 0; ni < 8; ++ni) {
                bf16x8 bfrag = *(const bf16x8*)(bsb + ni * (16 * 128));
                acc[0][ni] = __builtin_amdgcn_mfma_f32_16x16x32_bf16(a0, bfrag, acc[0][ni], 0, 0, 0);
                acc[1][ni] = __builtin_amdgcn_mfma_f32_16x16x32_bf16(a1, bfrag, acc[1][ni], 0, 0, 0);
            }
        }
        __builtin_amdgcn_sched_barrier(0);
        __builtin_amdgcn_s_barrier();
        __builtin_amdgcn_sched_barrier(0);
        if (c + 2 < NCH) STAGE(Bbuf[c & 1], c + 2);
        __builtin_amdgcn_sched_barrier(0);
        if (c + 1 < NCH)
            vmwait((c < NCH - 2) ? 8 : 0);
    }

    // ---- epilogue ----
    const int orow = (l >> 4) * 4, ocol = l & 15;
    if (Cb != nullptr) {
        const bool is2 = (Cb2 != nullptr) && (n0 >= DIM);
        u16* dst = is2 ? Cb2 : Cb;
        const int ldcs = is2 ? DIM : ldc;
        const int nc0 = is2 ? (n0 - DIM) : n0;
        const float* bp2 = is2 ? bias2 : bias;
        const int md = is2 ? mode2 : mode;
#pragma unroll
        for (int mi = 0; mi < 2; ++mi)
#pragma unroll
            for (int ni = 0; ni < 8; ++ni) {
                const int colL = ni * 16 + ocol;
                const float bv = bp2[nc0 + colL];
#pragma unroll
                for (int r = 0; r < 4; ++r) {
                    const int rowL = w * 32 + mi * 16 + orow + r;
                    float v = acc[mi][ni][r] + bv;
                    if (md == M_SILU)      v = siluf(v);
                    else if (md == M_ELU1) v = (v > 0.f) ? (v + 1.f) : __expf(v);
                    else if (md == M_GELU) v = geluf(v);
                    smem[rowL * 128 + (colL ^ ((rowL & 7) << 3))] = f2bf(v);
                }
            }
        __builtin_amdgcn_s_barrier();
        const int rr = tid >> 4, cc = tid & 15;
#pragma unroll
        for (int it = 0; it < 8; ++it) {
            const int row = it * 16 + rr;
            u16x8 v = *(const u16x8*)&smem[row * 128 + ((cc * 8) ^ ((row & 7) << 3))];
            *(u16x8*)(dst + (size_t)(m0 + row) * ldcs + nc0 + cc * 8) = v;
        }
    } else {
        float* smf = (float*)smem;       // [128][64] f32 = 32KB per pass, 2 passes
#pragma unroll
        for (int p = 0; p < 2; ++p) {
            if (p) __builtin_amdgcn_s_barrier();
#pragma unroll
            for (int mi = 0; mi < 2; ++mi)
#pragma unroll
                for (int ni = 0; ni < 4; ++ni) {
                    const int colL = ni * 16 + ocol;
                    const float bv = bias[n0 + p * 64 + colL];
#pragma unroll
                    for (int r = 0; r < 4; ++r) {
                        const int rowL = w * 32 + mi * 16 + orow + r;
                        float v = acc[mi][p * 4 + ni][r] + bv;
                        if (mode == M_SILU)      v = siluf(v);
                        else if (mode == M_ELU1) v = (v > 0.f) ? (v + 1.f) : __expf(v);
                        else if (mode == M_GELU) v = geluf(v);
                        smf[rowL * 64 + (colL ^ ((rowL & 3) << 4))] = v;
                    }
                }
            __builtin_amdgcn_s_barrier();
            const int rr = tid >> 4, cc = tid & 15;
#pragma unroll
            for (int it = 0; it < 8; ++it) {
                const int row = it * 16 + rr;
                float4 v = *(const float4*)&smf[row * 64 + ((cc * 4) ^ ((row & 3) << 4))];
                const size_t oi = (size_t)(m0 + row) * ldc + n0 + p * 64 + cc * 4;
                if (res) {
                    float4 rv = *(const float4*)(res + oi);
                    v.x += rv.x; v.y += rv.y; v.z += rv.z; v.w += rv.w;
                }
                *(float4*)(Cf + oi) = v;
            }
        }
    }
}

// ---------------- kmean: column mean of k (bf16, M x 384), two-stage ----------------
__global__ __launch_bounds__(384) void kmean_part_k(const u16* __restrict__ kbuf, float* __restrict__ part, int nb) {
    const int b = blockIdx.x, chunk = blockIdx.y;   // nb x 9
    const int c = threadIdx.x;
    const u16* p = kbuf + ((size_t)(b * L_TOK + chunk * 256)) * DIM + c;
    float s = 0.f;
    for (int n = 0; n < 256; ++n) s += bf2f(p[(size_t)n * DIM]);
    part[(size_t)(chunk * nb + b) * DIM + c] = s;
}

__global__ __launch_bounds__(384) void kmean_fin_k(const float* __restrict__ part, float* __restrict__ km, int nb) {
    const int b = blockIdx.x, c = threadIdx.x;
    float s = 0.f;
#pragma unroll
    for (int ch = 0; ch < 9; ++ch) s += part[(size_t)(ch * nb + b) * DIM + c];
    km[b * DIM + c] = s * (1.0f / L_TOK);
}

// ---------------- z: z[row] = 1/(q[row,:]·km[b,:] + 1e-6), one wave per row ----------------
__global__ __launch_bounds__(256) void z_k(const u16* __restrict__ q, const float* __restrict__ km,
                                           float* __restrict__ z) {
    const int dd = blockIdx.x;
    const int vb = (dd & 7) * (gridDim.x >> 3) + (dd >> 3);
    const int row = vb * 4 + (threadIdx.x >> 6);
    const int lane = threadIdx.x & 63;
    const int b = row / L_TOK;
    const u16* qr = q + (size_t)row * DIM;
    const float* kb = km + b * DIM;
    float s = 0.f;
#pragma unroll
    for (int i = 0; i < 6; ++i) { int c = lane + i * 64; s += bf2f(qr[c]) * kb[c]; }
#pragma unroll
    for (int o = 32; o > 0; o >>= 1) s += __shfl_xor(s, o, 64);
    if (lane == 0) z[row] = 1.0f / (s + 1e-6f);
}

// ---------------- kv partials: 4 n-chunks of 576 tokens each ----------------
__global__ __launch_bounds__(256) void kv_part_k(const u16* __restrict__ kbuf, const u16* __restrict__ xi,
                                                 const float* __restrict__ cosT, const float* __restrict__ sinT,
                                                 float* __restrict__ part) {
    const int bh = blockIdx.x >> 2, chunk = blockIdx.x & 3;
    const int b = bh / NHEADS, h = bh % NHEADS;
    __shared__ float ks[64][33];
    __shared__ float vs[64][33];
    const int tid = threadIdx.x;
    const int e0 = (tid & 15) * 2;
    const int d0 = (tid >> 4) * 2;
    float acc00 = 0.f, acc01 = 0.f, acc10 = 0.f, acc11 = 0.f;
    const int nbeg = chunk * 576, nend = nbeg + 576;
    for (int n0 = nbeg; n0 < nend; n0 += 64) {
#pragma unroll
        for (int j = 0; j < 4; ++j) {           // 1024 rope pairs
            int pi = tid + j * 256;
            int tn = pi >> 4;
            int pd = pi & 15;
            int n = n0 + tn;
            unsigned kk = *(const unsigned*)(kbuf + ((size_t)(b * L_TOK + n)) * DIM + h * 32 + pd * 2);
            float ka = bf2f((u16)(kk & 0xffffu)), kb2 = bf2f((u16)(kk >> 16));
            float cs = cosT[n * 192 + h * 16 + pd];
            float sn = sinT[n * 192 + h * 16 + pd];
            ks[tn][pd * 2]     = cs * ka - sn * kb2;
            ks[tn][pd * 2 + 1] = sn * ka + cs * kb2;
        }
#pragma unroll
        for (int j = 0; j < 4; ++j) {           // 2048 v elems as u16 pairs
            int pi = tid + j * 256;
            int tn = pi >> 4;
            int dd = (pi & 15) * 2;
            unsigned vv = *(const unsigned*)(xi + ((size_t)(b * L_TOK + n0 + tn)) * DIM + h * 32 + dd);
            vs[tn][dd]     = bf2f((u16)(vv & 0xffffu));
            vs[tn][dd + 1] = bf2f((u16)(vv >> 16));
        }
        __syncthreads();
#pragma unroll 8
        for (int n = 0; n < 64; ++n) {
            float k0v = ks[n][d0], k1v = ks[n][d0 + 1];
            float v0 = vs[n][e0], v1 = vs[n][e0 + 1];
            acc00 = fmaf(k0v, v0, acc00);
            acc01 = fmaf(k0v, v1, acc01);
            acc10 = fmaf(k1v, v0, acc10);
            acc11 = fmaf(k1v, v1, acc11);
        }
        __syncthreads();
    }
    float* o = part + ((size_t)blockIdx.x * 32 + d0) * 32 + e0;
    o[0] = acc00; o[1] = acc01;
    o[32] = acc10; o[33] = acc11;
}

// kv finalize -> bf16 TRANSPOSED: kvt[bh][e][d] = (1/L) * sum_chunks part[bh][d][e]
__global__ __launch_bounds__(256) void kv_fin_k(const float* __restrict__ part, u16* __restrict__ kvt) {
    const int bh = blockIdx.x;
    const int tid = threadIdx.x;
#pragma unroll
    for (int i = tid; i < 1024; i += 256) {
        const int e = i >> 5, dd = i & 31;
        float s = 0.f;
#pragma unroll
        for (int c = 0; c < 4; ++c) s += part[((size_t)(bh * 4 + c)) * 1024 + dd * 32 + e];
        kvt[(size_t)bh * 1024 + i] = f2bf(s * (1.0f / L_TOK));
    }
}

// ---------------- attention as MFMA ----------------
__global__ __launch_bounds__(256) void attm_k(const u16* __restrict__ q, const u16* __restrict__ kvt,
                                              const float* __restrict__ z,
                                              const float* __restrict__ cosT, const float* __restrict__ sinT,
                                              u16* __restrict__ out) {
    __shared__ u16 ost[128 * 32];        // 8 KB coalesce stage
    const int tid = threadIdx.x, l = tid & 63, w = tid >> 6;
    const int b = blockIdx.y / NHEADS, h = blockIdx.y % NHEADS;
    const int m0 = blockIdx.x * 128;
    const int fr = l & 15, kb = l >> 4;

    f32x4 acc[2][2];
#pragma unroll
    for (int i = 0; i < 2; ++i)
#pragma unroll
        for (int j = 0; j < 2; ++j) acc[i][j] = (f32x4){0.f, 0.f, 0.f, 0.f};

    const int p0 = h * 16 + kb * 4;      // rope pair base for this lane's 8 channels
    bf16x8 afr[2];
#pragma unroll
    for (int mi = 0; mi < 2; ++mi) {
        const int n = m0 + w * 32 + mi * 16 + fr;            // token index
        bf16x8 raw = *(const bf16x8*)(q + ((size_t)(b * L_TOK + n)) * DIM + h * 32 + kb * 8);
        float4 cs = *(const float4*)(cosT + (size_t)n * 192 + p0);
        float4 sn = *(const float4*)(sinT + (size_t)n * 192 + p0);
        union { u16 u[8]; bf16x8 v; } pk;
        float a0, a1;
        a0 = bf2f((u16)raw[0]); a1 = bf2f((u16)raw[1]);
        pk.u[0] = f2bf(cs.x * a0 - sn.x * a1); pk.u[1] = f2bf(sn.x * a0 + cs.x * a1);
        a0 = bf2f((u16)raw[2]); a1 = bf2f((u16)raw[3]);
        pk.u[2] = f2bf(cs.y * a0 - sn.y * a1); pk.u[3] = f2bf(sn.y * a0 + cs.y * a1);
        a0 = bf2f((u16)raw[4]); a1 = bf2f((u16)raw[5]);
        pk.u[4] = f2bf(cs.z * a0 - sn.z * a1); pk.u[5] = f2bf(sn.z * a0 + cs.z * a1);
        a0 = bf2f((u16)raw[6]); a1 = bf2f((u16)raw[7]);
        pk.u[6] = f2bf(cs.w * a0 - sn.w * a1); pk.u[7] = f2bf(sn.w * a0 + cs.w * a1);
        afr[mi] = pk.v;
    }
    bf16x8 bfr[2];
    const u16* kvh = kvt + (size_t)(b * NHEADS + h) * 1024;
#pragma unroll
    for (int ni = 0; ni < 2; ++ni)
        bfr[ni] = *(const bf16x8*)(kvh + (ni * 16 + fr) * 32 + kb * 8);
#pragma unroll
    for (int mi = 0; mi < 2; ++mi)
#pragma unroll
        for (int ni = 0; ni < 2; ++ni)
            acc[mi][ni] = __builtin_amdgcn_mfma_f32_16x16x32_bf16(afr[mi], bfr[ni], acc[mi][ni], 0, 0, 0);

    // epilogue: scale by z, stage to LDS, coalesced store
    const int orow = (l >> 4) * 4, ocol = l & 15;
#pragma unroll
    for (int mi = 0; mi < 2; ++mi) {
        float zz[4];
#pragma unroll
        for (int r = 0; r < 4; ++r)
            zz[r] = z[b * L_TOK + m0 + w * 32 + mi * 16 + orow + r];
#pragma unroll
        for (int ni = 0; ni < 2; ++ni) {
#pragma unroll
            for (int r = 0; r < 4; ++r) {
                const int rowL = w * 32 + mi * 16 + orow + r;
                ost[rowL * 32 + ni * 16 + ocol] = f2bf(acc[mi][ni][r] * zz[r]);
            }
        }
    }
    __syncthreads();
#pragma unroll
    for (int it = 0; it < 2; ++it) {
        const int ch = it * 256 + tid;               // 0..511
        const int row = ch >> 2, c8 = (ch & 3) * 8;
        u16x8 v = *(const u16x8*)&ost[row * 32 + c8];
        *(u16x8*)(out + ((size_t)(b * L_TOK + m0 + row)) * DIM + h * 32 + c8) = v;
    }
}

extern "C" void kernel_launch(void* const* d_in, const int* in_sizes, int n_in,
                              void* d_out, int out_size, void* d_ws, size_t ws_size,
                              hipStream_t stream) {
    const float* x       = (const float*)d_in[0];
    const float* cpe1_w  = (const float*)d_in[3];
    const float* cpe1_b  = (const float*)d_in[4];
    const float* norm1_w = (const float*)d_in[5];
    const float* norm1_b = (const float*)d_in[6];
    const float* in_w    = (const float*)d_in[7];
    const float* in_b    = (const float*)d_in[8];
    const float* act_w   = (const float*)d_in[9];
    const float* act_b   = (const float*)d_in[10];
    const float* dwc_w   = (const float*)d_in[11];
    const float* dwc_b   = (const float*)d_in[12];
    const float* qk_w    = (const float*)d_in[13];
    const float* qk_b    = (const float*)d_in[14];
    const float* lepe_w  = (const float*)d_in[15];
    const float* lepe_b  = (const float*)d_in[16];
    const float* outp_w  = (const float*)d_in[17];
    const float* outp_b  = (const float*)d_in[18];
    const float* cpe2_w  = (const float*)d_in[19];
    const float* cpe2_b  = (const float*)d_in[20];
    const float* norm2_w = (const float*)d_in[21];
    const float* norm2_b = (const float*)d_in[22];
    const float* fc1_w   = (const float*)d_in[23];
    const float* fc1_b   = (const float*)d_in[24];
    const float* fc2_w   = (const float*)d_in[25];
    const float* fc2_b   = (const float*)d_in[26];
    float* out = (float*)d_out;

    float* ws = (float*)d_ws;
    const size_t TAB = (size_t)L_TOK * 192;
    const size_t NW_IN = 147456, NW_QK = 294912, NW_FC = 589824;
    const size_t WBF_U16 = NW_IN * 3 + NW_QK + NW_FC * 2;
    const size_t KVP = 4 * (size_t)BATCH * NHEADS * 1024;          // kv partials
    const size_t ZB  = (size_t)BATCH * L_TOK;                      // z buffer
    const size_t SMALL = 2 * TAB + (size_t)BATCH * DIM + 9 * (size_t)BATCH * DIM
                       + (size_t)BATCH * NHEADS * 1024 + KVP + ZB + WBF_U16 / 2;
    float* cosT = ws;
    float* sinT = cosT + TAB;
    float* km   = sinT + TAB;
    float* part = km + (size_t)BATCH * DIM;
    float* kvb  = part + 9 * (size_t)BATCH * DIM;                  // kvt lives here (u16, half used)
    float* kvp  = kvb + (size_t)BATCH * NHEADS * 1024;
    float* zb   = kvp + KVP;
    u16*   kvt  = (u16*)kvb;
    u16*   wb_in  = (u16*)(zb + ZB);                               // [in_w; act_w] = 768x384
    u16*   wb_act = wb_in + NW_IN;
    u16*   wb_qk  = wb_act + NW_IN;                                // 768x384
    u16*   wb_out = wb_qk + NW_QK;
    u16*   wb_fc1 = wb_out + NW_IN;
    u16*   wb_fc2 = wb_fc1 + NW_FC;
    float* gbuf = ws + SMALL;

    const size_t avail = (ws_size / 4 > SMALL) ? (ws_size / 4 - SMALL) : 0;
    int nb = 0;
    for (int cand = BATCH; cand >= 1; cand >>= 1)
        if (9 * (size_t)cand * UNITB / 2 <= avail) { nb = cand; break; }
    if (nb == 0) {
        sentinel_k<<<1, 1, 0, stream>>>(out, (float)(ws_size >> 20));
        return;
    }

    cvtw_k<<<(int)(NW_IN / 1024), 256, 0, stream>>>(in_w, wb_in);
    cvtw_k<<<(int)(NW_IN / 1024), 256, 0, stream>>>(act_w, wb_act);
    cvtw_k<<<(int)(NW_QK / 1024), 256, 0, stream>>>(qk_w, wb_qk);
    cvtw_k<<<(int)(NW_IN / 1024), 256, 0, stream>>>(outp_w, wb_out);
    cvtw_k<<<(int)(NW_FC / 1024), 256, 0, stream>>>(fc1_w, wb_fc1);
    cvtw_k<<<(int)(NW_FC / 1024), 256, 0, stream>>>(fc2_w, wb_fc2);
    rope_tab_k<<<(int)((TAB + 255) / 256), 256, 0, stream>>>(cosT, sinT);

    for (int b0 = 0; b0 < BATCH; b0 += nb) {
        const size_t goff = (size_t)b0 * UNITB;
        const size_t GU   = (size_t)nb * UNITB;
        float* W0 = gbuf;             // x1 / x3 (f32 residual chain)
        float* W1 = gbuf + GU;        // xn(bf16) / q(bf16) / ao(bf16) / xn2(bf16)
        float* W2 = gbuf + 2 * GU;    // xi0+act_res(bf16) / x2(f32) / h(bf16, W2+W3)
        u16*   Wb = (u16*)(gbuf + 4 * GU);   // xi (bf16)
        float* O  = out + goff;       // k(bf16) / att(bf16) / final out (f32)
        const float* Xg = x + goff;
        u16* xi0p = (u16*)W2;         // xi0 bf16 (GU u16)
        u16* actp = (u16*)W2 + GU;    // act_res bf16 (GU u16)

        const dim3 DWG(18, nb * 4);
        const dim3 G384(3, nb * 18), G768(6, nb * 18), G1536(12, nb * 18);

        // x1 = x + dwconv(x, cpe1) -> W0 f32
        dwconvf_k<<<DWG, 256, 0, stream>>>(Xg, cpe1_w, cpe1_b, W0);
        // xn = LN(x1) -> W1 bf16
        ln_k<<<nb * 576, 256, 0, stream>>>(W0, norm1_w, norm1_b, (u16*)W1);
        // fused: xi0 = xn@in^T+b (cols<384) ; act_res = silu(xn@act^T+b) (cols>=384)
        gemm_sk<384><<<G768, 256, 0, stream>>>((u16*)W1, DIM, wb_in, DIM, in_b, act_b, nullptr,
                                               nullptr, xi0p, actp, DIM, M_BIAS, M_SILU);
        // xi = silu(dwconv(xi0, dwc)) -> Wb bf16
        dwconvb_k<<<DWG, 256, 0, stream>>>(xi0p, dwc_w, dwc_b, nullptr, nullptr, Wb, 1);
        // fused: q = elu(xi@qk[:384]^T+b)+1 -> W1 ; k = elu(xi@qk[384:]^T+b)+1 -> O
        gemm_sk<384><<<G768, 256, 0, stream>>>(Wb, DIM, wb_qk, DIM, qk_b, qk_b + DIM, nullptr,
                                               nullptr, (u16*)W1, (u16*)O, DIM, M_ELU1, M_ELU1);
        // kmean over k (bf16)
        kmean_part_k<<<dim3(nb, 9), 384, 0, stream>>>((u16*)O, part, nb);
        kmean_fin_k<<<nb, 384, 0, stream>>>(part, km, nb);
        // z = 1/(q·km + eps)
        z_k<<<nb * 576, 256, 0, stream>>>((u16*)W1, km, zb);
        // kv from rope(k), v=xi: 4-way n-chunked partials + bf16-transposed reduce
        kv_part_k<<<nb * NHEADS * 4, 256, 0, stream>>>((u16*)O, Wb, cosT, sinT, kvp);
        kv_fin_k<<<nb * NHEADS, 256, 0, stream>>>(kvp, kvt);
        // att = z * (rope(q) @ kv) -> O bf16 (overwrites k), MFMA path
        attm_k<<<dim3(18, nb * NHEADS), 256, 0, stream>>>((u16*)W1, kvt, zb, cosT, sinT, (u16*)O);
        // ao = (att + dwconv(xi, lepe)) * act_res -> W1 bf16
        dwconvb_k<<<DWG, 256, 0, stream>>>(Wb, lepe_w, lepe_b, (const u16*)O, actp,
                                           (u16*)W1, 3);
        // x2 = x1 + ao @ out_proj^T + b -> W2 f32 (act_res dead now)
        gemm_sk<384><<<G384, 256, 0, stream>>>((u16*)W1, DIM, wb_out, DIM, outp_b, nullptr, W0,
                                               W2, nullptr, nullptr, DIM, M_RES, M_RES);
        // x3 = x2 + dwconv(x2, cpe2) -> W0 f32
        dwconvf_k<<<DWG, 256, 0, stream>>>(W2, cpe2_w, cpe2_b, W0);
        // xn2 = LN(x3) -> W1 bf16
        ln_k<<<nb * 576, 256, 0, stream>>>(W0, norm2_w, norm2_b, (u16*)W1);
        // h = gelu(xn2 @ fc1^T + b) -> W2+W3 bf16
        gemm_sk<384><<<G1536, 256, 0, stream>>>((u16*)W1, DIM, wb_fc1, DIM, fc1_b, nullptr, nullptr,
                                                nullptr, (u16*)W2, nullptr, 1536, M_GELU, M_GELU);
        // O = x3 + h @ fc2^T + b2  (final, f32)
        gemm_sk<1536><<<G384, 256, 0, stream>>>((u16*)W2, 1536, wb_fc2, 1536, fc2_b, nullptr, W0,
                                                O, nullptr, nullptr, DIM, M_RES, M_RES);
    }
}